// Round 1
// baseline (2702.707 us; speedup 1.0000x reference)
//
#include <hip/hip_runtime.h>
#include <hip/hip_bf16.h>
#include <stdint.h>

#define T_DIM  128
#define TSTEPS 127      // T-1 sequential LSTM steps
#define BATCH  512
#define DDATA  512
#define HHID   512
#define NGATE  2048     // 4H
#define KTOT   1024     // D + H (fused K)
#define BH     262144   // BATCH*HHID

typedef _Float16 f16;
typedef _Float16 f16x8 __attribute__((ext_vector_type(8)));
typedef float    f32x4 __attribute__((ext_vector_type(4)));

// async global->LDS, 16B per lane. HW dest = wave-uniform base + lane*16;
// our per-lane pointers are affine (base + lane*16) so this matches exactly.
__device__ __forceinline__ void gl_lds16(const void* g, void* l) {
  __builtin_amdgcn_global_load_lds(
      (__attribute__((address_space(1))) void*)(g),
      (__attribute__((address_space(3))) void*)(l), 16, 0, 0);
}

// ---------------------------------------------------------------------------
// Prep: W16 reordered f16 B-operand, layout [nb(16)][kc(128)][col(128)][8]
// column index n = q*64 + g*16 + u  ->  original gate row R = g*512 + (q*16+u)
// so a wave's 64-col group holds all 4 gates for 16 h-columns.
// biasR[R] = b_ih[R] + b_hh[R] (identity layout, indexed as [g][j]).
// ---------------------------------------------------------------------------
__global__ void k_prep_w(const float* __restrict__ W_ih, const float* __restrict__ W_hh,
                         const float* __restrict__ b_ih, const float* __restrict__ b_hh,
                         f16* __restrict__ W16, float* __restrict__ biasR) {
  int n = blockIdx.x;                 // 0..2047 reordered col
  int q = n >> 6, g = (n >> 4) & 3, u = n & 15;
  int j = q * 16 + u;
  int R = g * 512 + j;
  int nb = n >> 7, col = n & 127;
  for (int k = threadIdx.x; k < KTOT; k += blockDim.x) {
    float v = (k < DDATA) ? W_ih[(size_t)R * DDATA + k]
                          : W_hh[(size_t)R * HHID + (k - DDATA)];
    int dst = nb * 131072 + (k >> 3) * 1024 + col * 8 + (k & 7);
    W16[dst] = (f16)v;
  }
  if (threadIdx.x == 0) biasR[R] = b_ih[R] + b_hh[R];
}

// X [B, T, D] f32  ->  XT [t][kc(64)][row(512)][8] f16 (A-operand layout)
__global__ void k_prep_x(const float* __restrict__ X, f16* __restrict__ XT) {
  int c = blockIdx.x * blockDim.x + threadIdx.x;   // 127*512*64 chunks of 8
  int t   = c >> 15;          // /(512*64)
  int rem = c & 32767;
  int kc  = rem >> 9;
  int row = rem & 511;
  const float* src = X + (size_t)row * (T_DIM * DDATA) + t * DDATA + kc * 8;
  f16x8 o;
#pragma unroll
  for (int e = 0; e < 8; e++) o[e] = (f16)src[e];
  *(f16x8*)(XT + (size_t)t * BH + kc * 4096 + row * 8) = o;
}

// ---------------------------------------------------------------------------
// One LSTM step: gates[512][2048] = [x_t | h] @ W16^T, fused cell update.
// Tile 32x128, grid (16 mb, 16 nb) = 256 WGs, 256 thr = 4 waves (2M x 2N).
// ---------------------------------------------------------------------------
__launch_bounds__(256)
__global__ void k_step(const f16* __restrict__ XTt,   // XT + t*BH
                       const f16* __restrict__ Hsrc,  // h16 src [kc64][512][8]
                       f16*       __restrict__ Hdst,  // h16 dst (next step A)
                       float*     __restrict__ Cst,   // c state [B][H] f32
                       float*     __restrict__ Hout,  // h_all + (t+1)*BH
                       const f16* __restrict__ W16,
                       const float* __restrict__ biasR) {
  __shared__ f16 Bs[4 * 128 * 8];   // 8KB  [kc][col][8]
  __shared__ f16 As[4 * 32 * 8];    // 2KB  [kc][row][8]
  const int tid = threadIdx.x;
  const int wid = tid >> 6, lane = tid & 63;
  const int wm = wid & 1, wn = wid >> 1;
  const int mb = blockIdx.x, nb = blockIdx.y;
  const int m0 = mb * 32;
  const int l15 = lane & 15, l4 = lane >> 4;

  f32x4 acc[4] = {};   // nf = gate 0..3 (i,f,g,o)

  for (int ks = 0; ks < 32; ks++) {
    int k0 = ks * 32;
    // stage B: 8KB = 8 x 1KB wave-chunks; wave w does chunks w and w+4
    {
      int s = wid * 64 + lane;
      int kc = s >> 7, colB = s & 127;
      gl_lds16(W16 + nb * 131072 + ((k0 >> 3) + kc) * 1024 + colB * 8,
               (void*)(Bs + s * 8));
      s += 256; kc = s >> 7; colB = s & 127;
      gl_lds16(W16 + nb * 131072 + ((k0 >> 3) + kc) * 1024 + colB * 8,
               (void*)(Bs + s * 8));
    }
    // stage A: 2KB = 2 x 1KB chunks; waves 2,3
    if (wid >= 2) {
      int s = (wid - 2) * 64 + lane;           // 0..127
      int kc = s >> 5, rowA = s & 31;
      int kg = (k0 >> 3) + kc;                  // global 8-chunk 0..127
      const f16* g = (kg < 64) ? (XTt  + kg        * 4096 + (m0 + rowA) * 8)
                               : (Hsrc + (kg - 64) * 4096 + (m0 + rowA) * 8);
      gl_lds16(g, (void*)(As + s * 8));
    }
    __syncthreads();
    f16x8 af = *(const f16x8*)(As + l4 * 256 + (wm * 16 + l15) * 8);
#pragma unroll
    for (int nf = 0; nf < 4; nf++) {
      f16x8 bf = *(const f16x8*)(Bs + l4 * 1024 + (wn * 64 + nf * 16 + l15) * 8);
      acc[nf] = __builtin_amdgcn_mfma_f32_16x16x32_f16(af, bf, acc[nf], 0, 0, 0);
    }
    __syncthreads();
  }

  // epilogue: lane owns 4 rows x 1 h-col x 4 gates
  int q = nb * 2 + wn;
  int j = q * 16 + l15;
  float bI = biasR[j], bF = biasR[512 + j], bG = biasR[1024 + j], bO = biasR[1536 + j];
#pragma unroll
  for (int r = 0; r < 4; r++) {
    int b = m0 + wm * 16 + l4 * 4 + r;
    float gi = acc[0][r] + bI;
    float gf = acc[1][r] + bF;
    float gg = acc[2][r] + bG;
    float go = acc[3][r] + bO;
    float ii = 1.f / (1.f + __expf(-gi));
    float ff = 1.f / (1.f + __expf(-gf));
    float eg = __expf(-2.f * fabsf(gg));
    float tg = copysignf((1.f - eg) / (1.f + eg), gg);   // tanh, NaN-safe
    float oo = 1.f / (1.f + __expf(-go));
    size_t cidx = (size_t)b * HHID + j;
    float c_new = ff * Cst[cidx] + ii * tg;
    Cst[cidx] = c_new;
    float ec = __expf(-2.f * fabsf(c_new));
    float th = copysignf((1.f - ec) / (1.f + ec), c_new);
    float h = oo * th;
    Hout[cidx] = h;
    Hdst[(j >> 3) * 4096 + b * 8 + (j & 7)] = (f16)h;
  }
}

// ---------------------------------------------------------------------------
// Tail: cosine-similarity attention over stored hidden states
// ---------------------------------------------------------------------------
__global__ void k_dots(const float* __restrict__ h_all, float* __restrict__ stats) {
  int t = blockIdx.x;   // 0..127 (127 = final; its nsq is the denom term)
  const f32x4* ht = (const f32x4*)(h_all + (size_t)t * BH);
  const f32x4* hf = (const f32x4*)(h_all + (size_t)127 * BH);
  float sn = 0.f, sq = 0.f;
  for (int i = threadIdx.x; i < BH / 4; i += blockDim.x) {
    f32x4 a = ht[i], b = hf[i];
    sn += a[0]*b[0] + a[1]*b[1] + a[2]*b[2] + a[3]*b[3];
    sq += a[0]*a[0] + a[1]*a[1] + a[2]*a[2] + a[3]*a[3];
  }
  for (int off = 32; off; off >>= 1) {
    sn += __shfl_down(sn, off);
    sq += __shfl_down(sq, off);
  }
  __shared__ float red[8];
  int wid = threadIdx.x >> 6;
  if ((threadIdx.x & 63) == 0) { red[wid] = sn; red[4 + wid] = sq; }
  __syncthreads();
  if (threadIdx.x == 0) {
    stats[t]       = red[0] + red[1] + red[2] + red[3];
    stats[128 + t] = red[4] + red[5] + red[6] + red[7];
  }
}

__global__ void k_softmax(float* __restrict__ stats) {
  __shared__ float logit[TSTEPS];
  int tid = threadIdx.x;
  float nf = fmaxf(sqrtf(stats[128 + 127]), 1e-8f);
  if (tid < TSTEPS) {
    float np = fmaxf(sqrtf(stats[128 + tid]), 1e-8f);
    logit[tid] = stats[tid] / (np * nf);
  }
  __syncthreads();
  if (tid == 0) {
    float m = -1e30f;
    for (int i = 0; i < TSTEPS; i++) m = fmaxf(m, logit[i]);
    float s = 0.f;
    for (int i = 0; i < TSTEPS; i++) { float e = __expf(logit[i] - m); logit[i] = e; s += e; }
    float inv = 1.f / s;
    for (int i = 0; i < TSTEPS; i++) stats[256 + i] = logit[i] * inv;
  }
}

__global__ void k_out(const float* __restrict__ h_all, const float* __restrict__ stats,
                      float* __restrict__ out) {
  __shared__ float al[TSTEPS];
  if (threadIdx.x < TSTEPS) al[threadIdx.x] = stats[256 + threadIdx.x];
  __syncthreads();
  int gid = blockIdx.x * blockDim.x + threadIdx.x;   // 0..65535 float4s
  f32x4 s = {0.f, 0.f, 0.f, 0.f};
  for (int t = 1; t < TSTEPS; t++) {                 // t=0 is all-zero h0
    f32x4 h = *(const f32x4*)(h_all + (size_t)t * BH + (size_t)gid * 4);
    float a = al[t];
    s[0] += a * h[0]; s[1] += a * h[1]; s[2] += a * h[2]; s[3] += a * h[3];
  }
  *(f32x4*)(out + (size_t)gid * 4) = s;
}

// ---------------------------------------------------------------------------
extern "C" void kernel_launch(void* const* d_in, const int* in_sizes, int n_in,
                              void* d_out, int out_size, void* d_ws, size_t ws_size,
                              hipStream_t stream) {
  const float* X    = (const float*)d_in[0];
  const float* W_ih = (const float*)d_in[1];
  const float* W_hh = (const float*)d_in[2];
  const float* b_ih = (const float*)d_in[3];
  const float* b_hh = (const float*)d_in[4];

  char* ws = (char*)d_ws;
  size_t off = 0;
  auto alloc = [&](size_t bytes) -> void* {
    void* p = ws + off;
    off = (off + bytes + 255) & ~(size_t)255;
    return p;
  };
  f16*   W16   = (f16*)  alloc((size_t)NGATE * KTOT * 2);   // 4 MB
  float* biasR = (float*)alloc(NGATE * 4);                  // 8 KB
  f16*   XT    = (f16*)  alloc((size_t)TSTEPS * BH * 2);    // 66 MB
  f16*   h16A  = (f16*)  alloc((size_t)BH * 2);             // 0.5 MB
  f16*   h16B  = (f16*)  alloc((size_t)BH * 2);             // 0.5 MB
  float* Cst   = (float*)alloc((size_t)BH * 4);             // 1 MB
  float* stats = (float*)alloc(512 * 4);                    // num/nsq/alpha
  float* h_all = (float*)alloc((size_t)T_DIM * BH * 4);     // 128 MB

  hipMemsetAsync(h16A,  0, (size_t)BH * 2, stream);
  hipMemsetAsync(Cst,   0, (size_t)BH * 4, stream);
  hipMemsetAsync(h_all, 0, (size_t)BH * 4, stream);  // h_all[0] = h0 = 0

  k_prep_w<<<NGATE, 128, 0, stream>>>(W_ih, W_hh, b_ih, b_hh, W16, biasR);
  k_prep_x<<<(TSTEPS * 512 * 64) / 256, 256, 0, stream>>>(X, XT);

  for (int t = 0; t < TSTEPS; t++) {
    const f16* hs = (t & 1) ? h16B : h16A;
    f16*       hd = (t & 1) ? h16A : h16B;
    k_step<<<dim3(16, 16), 256, 0, stream>>>(XT + (size_t)t * BH, hs, hd, Cst,
                                             h_all + (size_t)(t + 1) * BH,
                                             W16, biasR);
  }

  k_dots<<<128, 256, 0, stream>>>(h_all, stats);
  k_softmax<<<1, 128, 0, stream>>>(stats);
  k_out<<<256, 256, 0, stream>>>(h_all, stats, (float*)d_out);
}

// Round 2
// 1576.542 us; speedup vs baseline: 1.7143x; 1.7143x over previous
//
#include <hip/hip_runtime.h>
#include <stdint.h>

#define T_DIM  128
#define TSTEPS 127
#define BATCH  512
#define DDATA  512
#define HHID   512
#define BH     262144   // BATCH*HHID

typedef _Float16 f16;
typedef _Float16 f16x8 __attribute__((ext_vector_type(8)));
typedef float    f32x4 __attribute__((ext_vector_type(4)));
typedef unsigned long long u64;

#define MFMA16 __builtin_amdgcn_mfma_f32_16x16x32_f16

// agent-scope (sc0 sc1) 16B fragment load: bypasses non-coherent per-XCD L2s
__device__ __forceinline__ f16x8 ldh(const u64* p) {
  union { u64 u[2]; f16x8 v; } r;
  r.u[0] = __hip_atomic_load(p,     __ATOMIC_RELAXED, __HIP_MEMORY_SCOPE_AGENT);
  r.u[1] = __hip_atomic_load(p + 1, __ATOMIC_RELAXED, __HIP_MEMORY_SCOPE_AGENT);
  return r.v;
}

// ---------------------------------------------------------------------------
// W16B: f16 B-fragments, flat layout [nb16][kh2][wc4][fi=ks*2+nf 32][lane64][8]
// fragment (nb,kh,wc,nf,ks): col16 = lane&15 = hm*4+g ; k = kh*512+ks*32+(lane>>4)*8+e
// h column hg = (nb*4+wc)*8 + nf*4 + hm ; gate row R = g*512 + hg
// ---------------------------------------------------------------------------
__global__ void k_prep_w(const float* __restrict__ W_ih, const float* __restrict__ W_hh,
                         f16* __restrict__ W16B) {
  int d = blockIdx.x * blockDim.x + threadIdx.x;   // 0..262143
  int lane = d & 63;
  int fi   = (d >> 6) & 31;
  int ks = fi >> 1, nf = fi & 1;
  int wcv = (d >> 11) & 3;
  int khv = (d >> 13) & 1;
  int nbv = d >> 14;
  int col16 = lane & 15, lk2 = lane >> 4;
  int hm = col16 >> 2, g = col16 & 3;
  int hg = (nbv * 4 + wcv) * 8 + nf * 4 + hm;
  int R = g * 512 + hg;
  int kbase = khv * 512 + ks * 32 + lk2 * 8;
  const float* src = (kbase < 512) ? (W_ih + (size_t)R * 512 + kbase)
                                   : (W_hh + (size_t)R * 512 + (kbase - 512));
  f16x8 o;
#pragma unroll
  for (int e = 0; e < 8; e++) o[e] = (f16)src[e];
  *(f16x8*)(W16B + (size_t)d * 8) = o;
}

__global__ void k_prep_b(const float* __restrict__ b_ih, const float* __restrict__ b_hh,
                         float* __restrict__ biasR) {
  int r = blockIdx.x * blockDim.x + threadIdx.x;
  if (r < 2048) biasR[r] = b_ih[r] + b_hh[r];
}

// X [B, T, D] f32  ->  XT [t][kc(64)][row(512)][8] f16 (A-fragment layout)
__global__ void k_prep_x(const float* __restrict__ X, f16* __restrict__ XT) {
  int c = blockIdx.x * blockDim.x + threadIdx.x;   // 127*512*64
  int t   = c >> 15;
  int rem = c & 32767;
  int kc  = rem >> 9;
  int row = rem & 511;
  const float* src = X + (size_t)row * (T_DIM * DDATA) + t * DDATA + kc * 8;
  f16x8 o;
#pragma unroll
  for (int e = 0; e < 8; e++) o[e] = (f16)src[e];
  *(f16x8*)(XT + (size_t)t * BH + kc * 4096 + row * 8) = o;
}

// ---------------------------------------------------------------------------
// Persistent LSTM: 256 WGs (=CUs) x 512 thr. Weights in VGPRs for all steps.
// Waves: w>>2 = kh (0: x-half K<512, 1: h-half), w&3 = wc (32-col quadrant).
// Per-step: per-wave GEMM from registers/global -> LDS K-reduction -> fused
// cell update -> h f16 (agent-scope) -> per-mb flag.
// ---------------------------------------------------------------------------
__launch_bounds__(512, 2)
__global__ void k_lstm(const f16* __restrict__ XT, f16* __restrict__ h_all,
                       const f16* __restrict__ W16B, const float* __restrict__ biasR,
                       int* __restrict__ done) {
  __shared__ float C0[32][128];
  __shared__ float C1[32][128];
  __shared__ float BiasS[128];

  const int tid = threadIdx.x, lane = tid & 63, w = tid >> 6;
  const int kh = w >> 2, wc = w & 3;
  const int wg = blockIdx.x;
  const int mb = (wg & 7) * 2 + ((wg >> 3) & 1);   // same-mb group -> same XCD
  const int nb = wg >> 4;
  const int m0 = mb * 32;
  const int l15 = lane & 15, lk = lane >> 4;

  // persistent B fragments: 32 x f16x8 = 128 VGPRs
  f16x8 B[32];
  {
    const f16* wb = W16B + ((size_t)((nb * 2 + kh) * 4 + wc) * 32) * 512 + lane * 8;
#pragma unroll
    for (int i = 0; i < 32; i++) B[i] = *(const f16x8*)(wb + i * 512);
  }
  if (tid < 128) {
    int cl = tid;
    int g = cl & 3, hm = (cl >> 2) & 3, nf = (cl >> 4) & 1, wcv = cl >> 5;
    int h_loc = wcv * 8 + nf * 4 + hm;
    BiasS[cl] = biasR[g * 512 + nb * 32 + h_loc];
  }
  const int rloc = tid >> 4, hp = tid & 15;
  const int rowg = m0 + rloc;
  const int hg0 = nb * 32 + 2 * hp;   // even
  float c0 = 0.f, c1 = 0.f;
  __syncthreads();

  for (int t = 0; t < TSTEPS; t++) {
    f32x4 acc[2][2] = {};

    if (kh == 0) {
      const f16* Ab = XT + (size_t)t * BH + (size_t)lk * 4096 + (size_t)(m0 + l15) * 8;
#pragma unroll
      for (int ks = 0; ks < 16; ks++) {
        f16x8 a0 = *(const f16x8*)(Ab + (size_t)ks * 4 * 4096);
        f16x8 a1 = *(const f16x8*)(Ab + (size_t)ks * 4 * 4096 + 128);
        acc[0][0] = MFMA16(a0, B[2 * ks],     acc[0][0], 0, 0, 0);
        acc[0][1] = MFMA16(a0, B[2 * ks + 1], acc[0][1], 0, 0, 0);
        acc[1][0] = MFMA16(a1, B[2 * ks],     acc[1][0], 0, 0, 0);
        acc[1][1] = MFMA16(a1, B[2 * ks + 1], acc[1][1], 0, 0, 0);
      }
    } else {
      if (t > 0) {
        const int* flag = done + (t - 1) * 16 + mb;
        int spins = 0;
        while (__hip_atomic_load(flag, __ATOMIC_RELAXED, __HIP_MEMORY_SCOPE_AGENT) < 16) {
          __builtin_amdgcn_s_sleep(2);
          if (++spins > (1 << 22)) break;   // bounded: fail visibly, never hang
        }
      }
      const u64* Hb = (const u64*)(h_all + (size_t)t * BH) + (size_t)lk * 1024
                      + (size_t)(m0 + l15) * 2;
      f16x8 Ah[2][8];
#pragma unroll
      for (int blk = 0; blk < 4; blk++) {
        if (blk == 0) {
#pragma unroll
          for (int j = 0; j < 4; j++) {
            const u64* p = Hb + (size_t)j * 4096;
            Ah[0][j * 2]     = ldh(p);
            Ah[0][j * 2 + 1] = ldh(p + 32);
          }
        }
        if (blk < 3) {
#pragma unroll
          for (int j = 0; j < 4; j++) {
            const u64* p = Hb + (size_t)((blk + 1) * 4 + j) * 4096;
            Ah[(blk + 1) & 1][j * 2]     = ldh(p);
            Ah[(blk + 1) & 1][j * 2 + 1] = ldh(p + 32);
          }
        }
#pragma unroll
        for (int j = 0; j < 4; j++) {
          int ks = blk * 4 + j;
          f16x8 a0 = Ah[blk & 1][j * 2], a1 = Ah[blk & 1][j * 2 + 1];
          acc[0][0] = MFMA16(a0, B[2 * ks],     acc[0][0], 0, 0, 0);
          acc[0][1] = MFMA16(a0, B[2 * ks + 1], acc[0][1], 0, 0, 0);
          acc[1][0] = MFMA16(a1, B[2 * ks],     acc[1][0], 0, 0, 0);
          acc[1][1] = MFMA16(a1, B[2 * ks + 1], acc[1][1], 0, 0, 0);
        }
      }
    }

    // K-half partials -> LDS
    {
      float (*Cb)[128] = kh ? C1 : C0;
#pragma unroll
      for (int mf = 0; mf < 2; mf++)
#pragma unroll
        for (int nf = 0; nf < 2; nf++)
#pragma unroll
          for (int r = 0; r < 4; r++)
            Cb[mf * 16 + lk * 4 + r][wc * 32 + nf * 16 + l15] = acc[mf][nf][r];
    }
    __syncthreads();

    // fused cell update: thread -> (row rloc, h pair 2hp,2hp+1)
    {
      const float* p0 = &C0[rloc][hp * 8];
      const float* p1 = &C1[rloc][hp * 8];
      f32x4 u0 = *(const f32x4*)p0;
      f32x4 u1 = *(const f32x4*)(p0 + 4);
      f32x4 v0 = *(const f32x4*)p1;
      f32x4 v1 = *(const f32x4*)(p1 + 4);
      float gi0 = u0[0] + v0[0] + BiasS[hp * 8 + 0];
      float gf0 = u0[1] + v0[1] + BiasS[hp * 8 + 1];
      float gg0 = u0[2] + v0[2] + BiasS[hp * 8 + 2];
      float go0 = u0[3] + v0[3] + BiasS[hp * 8 + 3];
      float gi1 = u1[0] + v1[0] + BiasS[hp * 8 + 4];
      float gf1 = u1[1] + v1[1] + BiasS[hp * 8 + 5];
      float gg1 = u1[2] + v1[2] + BiasS[hp * 8 + 6];
      float go1 = u1[3] + v1[3] + BiasS[hp * 8 + 7];

      float i0 = 1.f / (1.f + __expf(-gi0));
      float f0 = 1.f / (1.f + __expf(-gf0));
      float e0 = __expf(-2.f * fabsf(gg0));
      float tg0 = copysignf((1.f - e0) / (1.f + e0), gg0);
      float o0 = 1.f / (1.f + __expf(-go0));
      c0 = f0 * c0 + i0 * tg0;
      float ec0 = __expf(-2.f * fabsf(c0));
      float th0 = copysignf((1.f - ec0) / (1.f + ec0), c0);
      float h0 = o0 * th0;

      float i1 = 1.f / (1.f + __expf(-gi1));
      float f1 = 1.f / (1.f + __expf(-gf1));
      float e1 = __expf(-2.f * fabsf(gg1));
      float tg1 = copysignf((1.f - e1) / (1.f + e1), gg1);
      float o1 = 1.f / (1.f + __expf(-go1));
      c1 = f1 * c1 + i1 * tg1;
      float ec1 = __expf(-2.f * fabsf(c1));
      float th1 = copysignf((1.f - ec1) / (1.f + ec1), c1);
      float h1 = o1 * th1;

      union { f16 h[2]; unsigned int u; } pk;
      pk.h[0] = (f16)h0; pk.h[1] = (f16)h1;
      unsigned int* dst = (unsigned int*)(h_all + (size_t)(t + 1) * BH
                          + (size_t)(hg0 >> 3) * 4096 + (size_t)rowg * 8 + (hg0 & 7));
      __hip_atomic_store(dst, pk.u, __ATOMIC_RELAXED, __HIP_MEMORY_SCOPE_AGENT);
    }
    __syncthreads();   // drains all waves' stores (vmcnt) + protects LDS reuse
    if (tid == 0)
      __hip_atomic_fetch_add(done + t * 16 + mb, 1, __ATOMIC_RELEASE,
                             __HIP_MEMORY_SCOPE_AGENT);
  }
}

// ---------------------------------------------------------------------------
// Tail: cosine-similarity attention (h_all is f16, layout-agnostic reductions)
// ---------------------------------------------------------------------------
__global__ void k_dots(const f16* __restrict__ h_all, float* __restrict__ part) {
  int t = blockIdx.x, s = blockIdx.y;
  const f16x8* ht = (const f16x8*)(h_all + (size_t)t * BH) + (size_t)s * 8192;
  const f16x8* hf = (const f16x8*)(h_all + (size_t)127 * BH) + (size_t)s * 8192;
  float sn = 0.f, sq = 0.f;
  for (int i = threadIdx.x; i < 8192; i += 256) {
    f16x8 a = ht[i], b = hf[i];
#pragma unroll
    for (int e = 0; e < 8; e++) {
      float fa = (float)a[e], fb = (float)b[e];
      sn += fa * fb; sq += fa * fa;
    }
  }
  for (int off = 32; off; off >>= 1) {
    sn += __shfl_down(sn, off);
    sq += __shfl_down(sq, off);
  }
  __shared__ float red[8];
  int wid = threadIdx.x >> 6;
  if ((threadIdx.x & 63) == 0) { red[wid] = sn; red[4 + wid] = sq; }
  __syncthreads();
  if (threadIdx.x == 0) {
    part[t * 8 + s]     = red[0] + red[1] + red[2] + red[3];
    part[t * 8 + 4 + s] = red[4] + red[5] + red[6] + red[7];
  }
}

__global__ void k_softmax(float* __restrict__ part) {
  __shared__ float sn_s[128], sq_s[128];
  int t = threadIdx.x;
  if (t < 128) {
    float sn = part[t * 8 + 0] + part[t * 8 + 1] + part[t * 8 + 2] + part[t * 8 + 3];
    float sq = part[t * 8 + 4] + part[t * 8 + 5] + part[t * 8 + 6] + part[t * 8 + 7];
    sn_s[t] = sn; sq_s[t] = sq;
  }
  __syncthreads();
  if (t == 0) {
    float nf = fmaxf(sqrtf(sq_s[127]), 1e-8f);
    float m = -1e30f;
    for (int i = 0; i < TSTEPS; i++) {
      float np = fmaxf(sqrtf(sq_s[i]), 1e-8f);
      sn_s[i] = sn_s[i] / (np * nf);
      m = fmaxf(m, sn_s[i]);
    }
    float ssum = 0.f;
    for (int i = 0; i < TSTEPS; i++) { float e = __expf(sn_s[i] - m); sn_s[i] = e; ssum += e; }
    float inv = 1.f / ssum;
    for (int i = 0; i < TSTEPS; i++) part[1024 + i] = sn_s[i] * inv;
  }
}

__global__ void k_out(const f16* __restrict__ h_all, const float* __restrict__ part,
                      float* __restrict__ out) {
  __shared__ float al[TSTEPS];
  if (threadIdx.x < TSTEPS) al[threadIdx.x] = part[1024 + threadIdx.x];
  __syncthreads();
  int g = blockIdx.x * blockDim.x + threadIdx.x;   // 0..32767
  int kc = g >> 9, row = g & 511;
  float s[8] = {0.f, 0.f, 0.f, 0.f, 0.f, 0.f, 0.f, 0.f};
  for (int t = 1; t < TSTEPS; t++) {               // t=0 is all-zero h0
    f16x8 v = *(const f16x8*)(h_all + (size_t)t * BH + (size_t)kc * 4096 + row * 8);
    float a = al[t];
#pragma unroll
    for (int e = 0; e < 8; e++) s[e] += a * (float)v[e];
  }
  float* o = out + (size_t)row * 512 + kc * 8;
  f32x4 lo = {s[0], s[1], s[2], s[3]}, hi = {s[4], s[5], s[6], s[7]};
  *(f32x4*)o = lo;
  *(f32x4*)(o + 4) = hi;
}

// ---------------------------------------------------------------------------
extern "C" void kernel_launch(void* const* d_in, const int* in_sizes, int n_in,
                              void* d_out, int out_size, void* d_ws, size_t ws_size,
                              hipStream_t stream) {
  const float* X    = (const float*)d_in[0];
  const float* W_ih = (const float*)d_in[1];
  const float* W_hh = (const float*)d_in[2];
  const float* b_ih = (const float*)d_in[3];
  const float* b_hh = (const float*)d_in[4];

  char* ws = (char*)d_ws;
  size_t off = 0;
  auto alloc = [&](size_t bytes) -> void* {
    void* p = ws + off;
    off = (off + bytes + 255) & ~(size_t)255;
    return p;
  };
  f16*   W16B  = (f16*)  alloc((size_t)2048 * 1024 * 2);    // 4 MB
  float* biasR = (float*)alloc(2048 * 4);                   // 8 KB
  f16*   XT    = (f16*)  alloc((size_t)TSTEPS * BH * 2);    // 66 MB
  f16*   h_all = (f16*)  alloc((size_t)T_DIM * BH * 2);     // 64 MB
  int*   done  = (int*)  alloc(TSTEPS * 16 * 4);            // 8 KB
  float* part  = (float*)alloc(2048 * 4);                   // 8 KB

  hipMemsetAsync(h_all, 0, (size_t)BH * 2, stream);   // h_all[0] = h0 = 0
  hipMemsetAsync(done,  0, TSTEPS * 16 * 4, stream);

  k_prep_w<<<1024, 256, 0, stream>>>(W_ih, W_hh, W16B);
  k_prep_b<<<8, 256, 0, stream>>>(b_ih, b_hh, biasR);
  k_prep_x<<<(TSTEPS * 512 * 64) / 256, 256, 0, stream>>>(X, XT);

  k_lstm<<<256, 512, 0, stream>>>(XT, h_all, W16B, biasR, done);

  k_dots<<<dim3(128, 4), 256, 0, stream>>>(h_all, part);
  k_softmax<<<1, 128, 0, stream>>>(part);
  k_out<<<128, 256, 0, stream>>>(h_all, part, (float*)d_out);
}

// Round 3
// 1056.350 us; speedup vs baseline: 2.5585x; 1.4924x over previous
//
#include <hip/hip_runtime.h>
#include <stdint.h>

#define T_DIM  128
#define TSTEPS 127
#define BATCH  512
#define DDATA  512
#define HHID   512
#define BH     262144   // BATCH*HHID
#define CPAD   144      // C-partial LDS stride: ==16 mod 32 -> 2-way (free)

typedef _Float16 f16;
typedef _Float16 f16x8 __attribute__((ext_vector_type(8)));
typedef float    f32x4 __attribute__((ext_vector_type(4)));
typedef unsigned long long u64;

#define MFMA16 __builtin_amdgcn_mfma_f32_16x16x32_f16

// agent-scope (sc0 sc1) 16B fragment load: bypasses non-coherent per-XCD L2s
__device__ __forceinline__ f16x8 ldh(const u64* p) {
  union { u64 u[2]; f16x8 v; } r;
  r.u[0] = __hip_atomic_load(p,     __ATOMIC_RELAXED, __HIP_MEMORY_SCOPE_AGENT);
  r.u[1] = __hip_atomic_load(p + 1, __ATOMIC_RELAXED, __HIP_MEMORY_SCOPE_AGENT);
  return r.v;
}

// ---------------------------------------------------------------------------
// W16B: f16 B-fragments, flat layout [nb16][kh2][wc4][fi=ks*2+nf 32][lane64][8]
// fragment (nb,kh,wc,nf,ks): col16 = lane&15 = hm*4+g ; k = kh*512+ks*32+(lane>>4)*8+e
// h column hg = (nb*4+wc)*8 + nf*4 + hm ; gate row R = g*512 + hg
// ---------------------------------------------------------------------------
__global__ void k_prep_w(const float* __restrict__ W_ih, const float* __restrict__ W_hh,
                         f16* __restrict__ W16B) {
  int d = blockIdx.x * blockDim.x + threadIdx.x;   // 0..262143
  int lane = d & 63;
  int fi   = (d >> 6) & 31;
  int ks = fi >> 1, nf = fi & 1;
  int wcv = (d >> 11) & 3;
  int khv = (d >> 13) & 1;
  int nbv = d >> 14;
  int col16 = lane & 15, lk2 = lane >> 4;
  int hm = col16 >> 2, g = col16 & 3;
  int hg = (nbv * 4 + wcv) * 8 + nf * 4 + hm;
  int R = g * 512 + hg;
  int kbase = khv * 512 + ks * 32 + lk2 * 8;
  const float* src = (kbase < 512) ? (W_ih + (size_t)R * 512 + kbase)
                                   : (W_hh + (size_t)R * 512 + (kbase - 512));
  f16x8 o;
#pragma unroll
  for (int e = 0; e < 8; e++) o[e] = (f16)src[e];
  *(f16x8*)(W16B + (size_t)d * 8) = o;
}

__global__ void k_prep_b(const float* __restrict__ b_ih, const float* __restrict__ b_hh,
                         float* __restrict__ biasR) {
  int r = blockIdx.x * blockDim.x + threadIdx.x;
  if (r < 2048) biasR[r] = b_ih[r] + b_hh[r];
}

// X [B, T, D] f32  ->  XT [t][kc(64)][row(512)][8] f16 (A-fragment layout)
__global__ void k_prep_x(const float* __restrict__ X, f16* __restrict__ XT) {
  int c = blockIdx.x * blockDim.x + threadIdx.x;   // 127*512*64
  int t   = c >> 15;
  int rem = c & 32767;
  int kc  = rem >> 9;
  int row = rem & 511;
  const float* src = X + (size_t)row * (T_DIM * DDATA) + t * DDATA + kc * 8;
  f16x8 o;
#pragma unroll
  for (int e = 0; e < 8; e++) o[e] = (f16)src[e];
  *(f16x8*)(XT + (size_t)t * BH + kc * 4096 + row * 8) = o;
}

// ---------------------------------------------------------------------------
// Persistent LSTM: 256 WGs (=CUs) x 512 thr, 1 WG/CU. Weights resident in
// VGPRs (B[32] = 128 VGPRs/wave) for all 127 steps — launch_bounds(512,1)
// gives the 256-VGPR budget that makes this possible.
// Waves: w>>2 = kh (0: x-half K<512, 1: h-half), w&3 = wc (32-col quadrant).
// ---------------------------------------------------------------------------
__launch_bounds__(512, 1)
__global__ void k_lstm(const f16* __restrict__ XT, f16* __restrict__ h_all,
                       const f16* __restrict__ W16B, const float* __restrict__ biasR,
                       int* __restrict__ done) {
  __shared__ float C0[32][CPAD];
  __shared__ float C1[32][CPAD];
  __shared__ float BiasS[128];

  const int tid = threadIdx.x, lane = tid & 63, w = tid >> 6;
  const int kh = w >> 2, wc = w & 3;
  const int wg = blockIdx.x;
  const int mb = (wg & 7) * 2 + ((wg >> 3) & 1);   // same-mb group -> same XCD
  const int nb = wg >> 4;
  const int m0 = mb * 32;
  const int l15 = lane & 15, lk = lane >> 4;

  // persistent B fragments: 32 x f16x8 = 128 VGPRs
  f16x8 B[32];
  {
    const f16* wb = W16B + ((size_t)((nb * 2 + kh) * 4 + wc) * 32) * 512 + lane * 8;
#pragma unroll
    for (int i = 0; i < 32; i++) B[i] = *(const f16x8*)(wb + i * 512);
  }
  if (tid < 128) {
    int cl = tid;
    int g = cl & 3, hm = (cl >> 2) & 3, nf = (cl >> 4) & 1, wcv = cl >> 5;
    int h_loc = wcv * 8 + nf * 4 + hm;
    BiasS[cl] = biasR[g * 512 + nb * 32 + h_loc];
  }
  const int rloc = tid >> 4, hp = tid & 15;
  const int rowg = m0 + rloc;
  const int hg0 = nb * 32 + 2 * hp;   // even
  float c0 = 0.f, c1 = 0.f;
  __syncthreads();

  for (int t = 0; t < TSTEPS; t++) {
    f32x4 acc[2][2] = {};

    if (kh == 0) {
      const f16* Ab = XT + (size_t)t * BH + (size_t)lk * 4096 + (size_t)(m0 + l15) * 8;
#pragma unroll
      for (int ks = 0; ks < 16; ks++) {
        f16x8 a0 = *(const f16x8*)(Ab + (size_t)ks * 4 * 4096);
        f16x8 a1 = *(const f16x8*)(Ab + (size_t)ks * 4 * 4096 + 128);
        acc[0][0] = MFMA16(a0, B[2 * ks],     acc[0][0], 0, 0, 0);
        acc[0][1] = MFMA16(a0, B[2 * ks + 1], acc[0][1], 0, 0, 0);
        acc[1][0] = MFMA16(a1, B[2 * ks],     acc[1][0], 0, 0, 0);
        acc[1][1] = MFMA16(a1, B[2 * ks + 1], acc[1][1], 0, 0, 0);
      }
    } else {
      if (t > 0) {
        const int* flag = done + (t - 1) * 16 + mb;
        int spins = 0;
        while (__hip_atomic_load(flag, __ATOMIC_RELAXED, __HIP_MEMORY_SCOPE_AGENT) < 16) {
          __builtin_amdgcn_s_sleep(1);
          if (++spins > (1 << 22)) break;   // bounded: fail visibly, never hang
        }
      }
      const u64* Hb = (const u64*)(h_all + (size_t)t * BH) + (size_t)lk * 1024
                      + (size_t)(m0 + l15) * 2;
      f16x8 Ah[2][8];
#pragma unroll
      for (int blk = 0; blk < 4; blk++) {
        if (blk == 0) {
#pragma unroll
          for (int j = 0; j < 4; j++) {
            const u64* p = Hb + (size_t)j * 4096;
            Ah[0][j * 2]     = ldh(p);
            Ah[0][j * 2 + 1] = ldh(p + 32);
          }
        }
        if (blk < 3) {
#pragma unroll
          for (int j = 0; j < 4; j++) {
            const u64* p = Hb + (size_t)((blk + 1) * 4 + j) * 4096;
            Ah[(blk + 1) & 1][j * 2]     = ldh(p);
            Ah[(blk + 1) & 1][j * 2 + 1] = ldh(p + 32);
          }
        }
#pragma unroll
        for (int j = 0; j < 4; j++) {
          int ks = blk * 4 + j;
          f16x8 a0 = Ah[blk & 1][j * 2], a1 = Ah[blk & 1][j * 2 + 1];
          acc[0][0] = MFMA16(a0, B[2 * ks],     acc[0][0], 0, 0, 0);
          acc[0][1] = MFMA16(a0, B[2 * ks + 1], acc[0][1], 0, 0, 0);
          acc[1][0] = MFMA16(a1, B[2 * ks],     acc[1][0], 0, 0, 0);
          acc[1][1] = MFMA16(a1, B[2 * ks + 1], acc[1][1], 0, 0, 0);
        }
      }
    }

    // K-half partials -> LDS (stride CPAD==16 mod 32 -> uniform 2-way, free)
    {
      float (*Cb)[CPAD] = kh ? C1 : C0;
#pragma unroll
      for (int mf = 0; mf < 2; mf++)
#pragma unroll
        for (int nf = 0; nf < 2; nf++)
#pragma unroll
          for (int r = 0; r < 4; r++)
            Cb[mf * 16 + lk * 4 + r][wc * 32 + nf * 16 + l15] = acc[mf][nf][r];
    }
    __syncthreads();

    // fused cell update: thread -> (row rloc, h pair 2hp,2hp+1)
    {
      const float* p0 = &C0[rloc][hp * 8];
      const float* p1 = &C1[rloc][hp * 8];
      f32x4 u0 = *(const f32x4*)p0;
      f32x4 u1 = *(const f32x4*)(p0 + 4);
      f32x4 v0 = *(const f32x4*)p1;
      f32x4 v1 = *(const f32x4*)(p1 + 4);
      float gi0 = u0[0] + v0[0] + BiasS[hp * 8 + 0];
      float gf0 = u0[1] + v0[1] + BiasS[hp * 8 + 1];
      float gg0 = u0[2] + v0[2] + BiasS[hp * 8 + 2];
      float go0 = u0[3] + v0[3] + BiasS[hp * 8 + 3];
      float gi1 = u1[0] + v1[0] + BiasS[hp * 8 + 4];
      float gf1 = u1[1] + v1[1] + BiasS[hp * 8 + 5];
      float gg1 = u1[2] + v1[2] + BiasS[hp * 8 + 6];
      float go1 = u1[3] + v1[3] + BiasS[hp * 8 + 7];

      float i0 = 1.f / (1.f + __expf(-gi0));
      float f0 = 1.f / (1.f + __expf(-gf0));
      float e0 = __expf(-2.f * fabsf(gg0));
      float tg0 = copysignf((1.f - e0) / (1.f + e0), gg0);
      float o0 = 1.f / (1.f + __expf(-go0));
      c0 = f0 * c0 + i0 * tg0;
      float ec0 = __expf(-2.f * fabsf(c0));
      float th0 = copysignf((1.f - ec0) / (1.f + ec0), c0);
      float h0 = o0 * th0;

      float i1 = 1.f / (1.f + __expf(-gi1));
      float f1 = 1.f / (1.f + __expf(-gf1));
      float e1 = __expf(-2.f * fabsf(gg1));
      float tg1 = copysignf((1.f - e1) / (1.f + e1), gg1);
      float o1 = 1.f / (1.f + __expf(-go1));
      c1 = f1 * c1 + i1 * tg1;
      float ec1 = __expf(-2.f * fabsf(c1));
      float th1 = copysignf((1.f - ec1) / (1.f + ec1), c1);
      float h1 = o1 * th1;

      union { f16 h[2]; unsigned int u; } pk;
      pk.h[0] = (f16)h0; pk.h[1] = (f16)h1;
      unsigned int* dst = (unsigned int*)(h_all + (size_t)(t + 1) * BH
                          + (size_t)(hg0 >> 3) * 4096 + (size_t)rowg * 8 + (hg0 & 7));
      __hip_atomic_store(dst, pk.u, __ATOMIC_RELAXED, __HIP_MEMORY_SCOPE_AGENT);
    }
    // __syncthreads drains vmcnt(0): all waves' sc0sc1 h-stores are ACKed at
    // LLC before any thread proceeds -> RELAXED flag add is ordered-enough
    // (avoids the agent-RELEASE buffer_wbl2 L2 writeback per step).
    __syncthreads();
    if (tid == 0)
      __hip_atomic_fetch_add(done + t * 16 + mb, 1, __ATOMIC_RELAXED,
                             __HIP_MEMORY_SCOPE_AGENT);
  }
}

// ---------------------------------------------------------------------------
// Tail: cosine-similarity attention (h_all is f16, layout-agnostic reductions)
// ---------------------------------------------------------------------------
__global__ void k_dots(const f16* __restrict__ h_all, float* __restrict__ part) {
  int t = blockIdx.x, s = blockIdx.y;
  const f16x8* ht = (const f16x8*)(h_all + (size_t)t * BH) + (size_t)s * 8192;
  const f16x8* hf = (const f16x8*)(h_all + (size_t)127 * BH) + (size_t)s * 8192;
  float sn = 0.f, sq = 0.f;
  for (int i = threadIdx.x; i < 8192; i += 256) {
    f16x8 a = ht[i], b = hf[i];
#pragma unroll
    for (int e = 0; e < 8; e++) {
      float fa = (float)a[e], fb = (float)b[e];
      sn += fa * fb; sq += fa * fa;
    }
  }
  for (int off = 32; off; off >>= 1) {
    sn += __shfl_down(sn, off);
    sq += __shfl_down(sq, off);
  }
  __shared__ float red[8];
  int wid = threadIdx.x >> 6;
  if ((threadIdx.x & 63) == 0) { red[wid] = sn; red[4 + wid] = sq; }
  __syncthreads();
  if (threadIdx.x == 0) {
    part[t * 8 + s]     = red[0] + red[1] + red[2] + red[3];
    part[t * 8 + 4 + s] = red[4] + red[5] + red[6] + red[7];
  }
}

__global__ void k_softmax(float* __restrict__ part) {
  __shared__ float sn_s[128], sq_s[128];
  int t = threadIdx.x;
  if (t < 128) {
    float sn = part[t * 8 + 0] + part[t * 8 + 1] + part[t * 8 + 2] + part[t * 8 + 3];
    float sq = part[t * 8 + 4] + part[t * 8 + 5] + part[t * 8 + 6] + part[t * 8 + 7];
    sn_s[t] = sn; sq_s[t] = sq;
  }
  __syncthreads();
  if (t == 0) {
    float nf = fmaxf(sqrtf(sq_s[127]), 1e-8f);
    float m = -1e30f;
    for (int i = 0; i < TSTEPS; i++) {
      float np = fmaxf(sqrtf(sq_s[i]), 1e-8f);
      sn_s[i] = sn_s[i] / (np * nf);
      m = fmaxf(m, sn_s[i]);
    }
    float ssum = 0.f;
    for (int i = 0; i < TSTEPS; i++) { float e = __expf(sn_s[i] - m); sn_s[i] = e; ssum += e; }
    float inv = 1.f / ssum;
    for (int i = 0; i < TSTEPS; i++) part[1024 + i] = sn_s[i] * inv;
  }
}

__global__ void k_out(const f16* __restrict__ h_all, const float* __restrict__ part,
                      float* __restrict__ out) {
  __shared__ float al[TSTEPS];
  if (threadIdx.x < TSTEPS) al[threadIdx.x] = part[1024 + threadIdx.x];
  __syncthreads();
  int g = blockIdx.x * blockDim.x + threadIdx.x;   // 0..32767
  int kc = g >> 9, row = g & 511;
  float s[8] = {0.f, 0.f, 0.f, 0.f, 0.f, 0.f, 0.f, 0.f};
  for (int t = 1; t < TSTEPS; t++) {               // t=0 is all-zero h0
    f16x8 v = *(const f16x8*)(h_all + (size_t)t * BH + (size_t)kc * 4096 + row * 8);
    float a = al[t];
#pragma unroll
    for (int e = 0; e < 8; e++) s[e] += a * (float)v[e];
  }
  float* o = out + (size_t)row * 512 + kc * 8;
  f32x4 lo = {s[0], s[1], s[2], s[3]}, hi = {s[4], s[5], s[6], s[7]};
  *(f32x4*)o = lo;
  *(f32x4*)(o + 4) = hi;
}

// ---------------------------------------------------------------------------
extern "C" void kernel_launch(void* const* d_in, const int* in_sizes, int n_in,
                              void* d_out, int out_size, void* d_ws, size_t ws_size,
                              hipStream_t stream) {
  const float* X    = (const float*)d_in[0];
  const float* W_ih = (const float*)d_in[1];
  const float* W_hh = (const float*)d_in[2];
  const float* b_ih = (const float*)d_in[3];
  const float* b_hh = (const float*)d_in[4];

  char* ws = (char*)d_ws;
  size_t off = 0;
  auto alloc = [&](size_t bytes) -> void* {
    void* p = ws + off;
    off = (off + bytes + 255) & ~(size_t)255;
    return p;
  };
  f16*   W16B  = (f16*)  alloc((size_t)2048 * 1024 * 2);    // 4 MB
  float* biasR = (float*)alloc(2048 * 4);                   // 8 KB
  f16*   XT    = (f16*)  alloc((size_t)TSTEPS * BH * 2);    // 66 MB
  f16*   h_all = (f16*)  alloc((size_t)T_DIM * BH * 2);     // 64 MB
  int*   done  = (int*)  alloc(TSTEPS * 16 * 4);            // 8 KB
  float* part  = (float*)alloc(2048 * 4);                   // 8 KB

  hipMemsetAsync(h_all, 0, (size_t)BH * 2, stream);   // h_all[0] = h0 = 0
  hipMemsetAsync(done,  0, TSTEPS * 16 * 4, stream);

  k_prep_w<<<1024, 256, 0, stream>>>(W_ih, W_hh, W16B);
  k_prep_b<<<8, 256, 0, stream>>>(b_ih, b_hh, biasR);
  k_prep_x<<<(TSTEPS * 512 * 64) / 256, 256, 0, stream>>>(X, XT);

  k_lstm<<<256, 512, 0, stream>>>(XT, h_all, W16B, biasR, done);

  k_dots<<<dim3(128, 4), 256, 0, stream>>>(h_all, part);
  k_softmax<<<1, 128, 0, stream>>>(part);
  k_out<<<128, 256, 0, stream>>>(h_all, part, (float*)d_out);
}

// Round 4
// 985.246 us; speedup vs baseline: 2.7432x; 1.0722x over previous
//
#include <hip/hip_runtime.h>
#include <stdint.h>

#define T_DIM  128
#define TSTEPS 127
#define BATCH  512
#define DDATA  512
#define HHID   512
#define BH     262144   // BATCH*HHID
#define CPAD   132      // 4*132 % 32 == 16 -> lk-pairs 2-way (free); 132%4==0 keeps b128 align

typedef _Float16 f16;
typedef _Float16 f16x8 __attribute__((ext_vector_type(8)));
typedef float    f32x4 __attribute__((ext_vector_type(4)));
typedef unsigned long long u64;

#define MFMA16 __builtin_amdgcn_mfma_f32_16x16x32_f16

// asm loads: result is asm-defined -> compiler CANNOT rematerialize; value
// stays VGPR-resident from def to last use. Caller manages s_waitcnt.
__device__ __forceinline__ f16x8 ld16(const f16* p) {          // plain
  f16x8 r;
  asm volatile("global_load_dwordx4 %0, %1, off" : "=v"(r) : "v"(p));
  return r;
}
__device__ __forceinline__ f16x8 ld16cc(const f16* p) {        // LLC-coherent
  f16x8 r;
  asm volatile("global_load_dwordx4 %0, %1, off sc0 sc1" : "=v"(r) : "v"(p));
  return r;
}

// ---------------------------------------------------------------------------
// W16B: f16 B-fragments, flat layout [nb16][kh2][wc4][fi=ks*2+nf 32][lane64][8]
// fragment (nb,kh,wc,nf,ks): col16 = lane&15 = hm*4+g ; k = kh*512+ks*32+(lane>>4)*8+e
// h column hg = (nb*4+wc)*8 + nf*4 + hm ; gate row R = g*512 + hg
// ---------------------------------------------------------------------------
__global__ void k_prep_w(const float* __restrict__ W_ih, const float* __restrict__ W_hh,
                         f16* __restrict__ W16B) {
  int d = blockIdx.x * blockDim.x + threadIdx.x;   // 0..262143
  int lane = d & 63;
  int fi   = (d >> 6) & 31;
  int ks = fi >> 1, nf = fi & 1;
  int wcv = (d >> 11) & 3;
  int khv = (d >> 13) & 1;
  int nbv = d >> 14;
  int col16 = lane & 15, lk2 = lane >> 4;
  int hm = col16 >> 2, g = col16 & 3;
  int hg = (nbv * 4 + wcv) * 8 + nf * 4 + hm;
  int R = g * 512 + hg;
  int kbase = khv * 512 + ks * 32 + lk2 * 8;
  const float* src = (kbase < 512) ? (W_ih + (size_t)R * 512 + kbase)
                                   : (W_hh + (size_t)R * 512 + (kbase - 512));
  f16x8 o;
#pragma unroll
  for (int e = 0; e < 8; e++) o[e] = (f16)src[e];
  *(f16x8*)(W16B + (size_t)d * 8) = o;
}

__global__ void k_prep_b(const float* __restrict__ b_ih, const float* __restrict__ b_hh,
                         float* __restrict__ biasR) {
  int r = blockIdx.x * blockDim.x + threadIdx.x;
  if (r < 2048) biasR[r] = b_ih[r] + b_hh[r];
}

// X [B, T, D] f32  ->  XT [t][kc(64)][row(512)][8] f16 (A-fragment layout)
__global__ void k_prep_x(const float* __restrict__ X, f16* __restrict__ XT) {
  int c = blockIdx.x * blockDim.x + threadIdx.x;   // 127*512*64
  int t   = c >> 15;
  int rem = c & 32767;
  int kc  = rem >> 9;
  int row = rem & 511;
  const float* src = X + (size_t)row * (T_DIM * DDATA) + t * DDATA + kc * 8;
  f16x8 o;
#pragma unroll
  for (int e = 0; e < 8; e++) o[e] = (f16)src[e];
  *(f16x8*)(XT + (size_t)t * BH + kc * 4096 + row * 8) = o;
}

// ---------------------------------------------------------------------------
// Persistent LSTM: 256 WGs (=CUs) x 512 thr, 1 WG/CU. Weights pinned in VGPRs
// via asm loads (B[32] = 128 VGPRs/wave, non-rematerializable).
// Waves: w>>2 = kh (0: x-half K<512, 1: h-half), w&3 = wc (32-col quadrant).
// ---------------------------------------------------------------------------
__launch_bounds__(512, 2)
__global__ void k_lstm(const f16* __restrict__ XT, f16* __restrict__ h_all,
                       const f16* __restrict__ W16B, const float* __restrict__ biasR,
                       int* __restrict__ done) {
  __shared__ float C0[32][CPAD];
  __shared__ float C1[32][CPAD];
  __shared__ float BiasS[128];

  const int tid = threadIdx.x, lane = tid & 63, w = tid >> 6;
  const int kh = w >> 2, wc = w & 3;
  const int wg = blockIdx.x;
  const int mb = (wg & 7) * 2 + ((wg >> 3) & 1);   // same-mb group -> same XCD
  const int nb = wg >> 4;
  const int m0 = mb * 32;
  const int l15 = lane & 15, lk = lane >> 4;

  // persistent B fragments: 32 x f16x8 = 128 VGPRs, pinned by asm defs
  f16x8 B[32];
  {
    const f16* wb = W16B + ((size_t)((nb * 2 + kh) * 4 + wc) * 32) * 512 + lane * 8;
#pragma unroll
    for (int i = 0; i < 32; i++) B[i] = ld16(wb + i * 512);
    asm volatile("s_waitcnt vmcnt(0)" ::: "memory");
    __builtin_amdgcn_sched_barrier(0);
  }
  if (tid < 128) {
    int cl = tid;
    int g = cl & 3, hm = (cl >> 2) & 3, nf = (cl >> 4) & 1, wcv = cl >> 5;
    int h_loc = wcv * 8 + nf * 4 + hm;
    BiasS[cl] = biasR[g * 512 + nb * 32 + h_loc];
  }
  const int rloc = tid >> 4, hp = tid & 15;
  const int rowg = m0 + rloc;
  const int hg0 = nb * 32 + 2 * hp;   // even
  float c0 = 0.f, c1 = 0.f;
  __syncthreads();
  // bias is loop-invariant: hoist into registers, drop per-step LDS reads
  float bv[8];
#pragma unroll
  for (int e = 0; e < 8; e++) bv[e] = BiasS[hp * 8 + e];

  unsigned int* hdst_base = (unsigned int*)(h_all
      + (size_t)(hg0 >> 3) * 4096 + (size_t)rowg * 8 + (hg0 & 7));

  for (int t = 0; t < TSTEPS; t++) {
    f32x4 acc[2][2] = {};

    if (kh == 0) {
      const f16* Ab = XT + (size_t)t * BH + (size_t)lk * 4096 + (size_t)(m0 + l15) * 8;
#pragma unroll
      for (int ks = 0; ks < 16; ks++) {
        f16x8 a0 = *(const f16x8*)(Ab + (size_t)ks * 16384);
        f16x8 a1 = *(const f16x8*)(Ab + (size_t)ks * 16384 + 128);
        acc[0][0] = MFMA16(a0, B[2 * ks],     acc[0][0], 0, 0, 0);
        acc[0][1] = MFMA16(a0, B[2 * ks + 1], acc[0][1], 0, 0, 0);
        acc[1][0] = MFMA16(a1, B[2 * ks],     acc[1][0], 0, 0, 0);
        acc[1][1] = MFMA16(a1, B[2 * ks + 1], acc[1][1], 0, 0, 0);
      }
    } else {
      if (t > 0) {
        const int* flag = done + (t - 1) * 16 + mb;
        int spins = 0;
        while (__hip_atomic_load(flag, __ATOMIC_RELAXED, __HIP_MEMORY_SCOPE_AGENT) < 16) {
          __builtin_amdgcn_s_sleep(1);
          if (++spins > (1 << 22)) break;   // bounded: fail visibly, never hang
        }
      }
      const f16* Hb = h_all + (size_t)t * BH + (size_t)lk * 4096 + (size_t)(m0 + l15) * 8;
      // counted-vmcnt double-buffered pipeline: 2 buffers x (4 ks x 2 m) frags
      f16x8 R0[8], R1[8];
#define ISSUE8(R, KS0)                                                        \
      {                                                                       \
        _Pragma("unroll")                                                     \
        for (int s = 0; s < 4; s++) {                                         \
          R[2 * s]     = ld16cc(Hb + (size_t)(KS0 + s) * 16384);              \
          R[2 * s + 1] = ld16cc(Hb + (size_t)(KS0 + s) * 16384 + 128);        \
        }                                                                     \
      }
#define MFMA8(R, KS0)                                                         \
      {                                                                       \
        _Pragma("unroll")                                                     \
        for (int s = 0; s < 4; s++) {                                         \
          int ks = KS0 + s;                                                   \
          acc[0][0] = MFMA16(R[2 * s],     B[2 * ks],     acc[0][0], 0, 0, 0);\
          acc[0][1] = MFMA16(R[2 * s],     B[2 * ks + 1], acc[0][1], 0, 0, 0);\
          acc[1][0] = MFMA16(R[2 * s + 1], B[2 * ks],     acc[1][0], 0, 0, 0);\
          acc[1][1] = MFMA16(R[2 * s + 1], B[2 * ks + 1], acc[1][1], 0, 0, 0);\
        }                                                                     \
      }
#define WAITV(N) asm volatile("s_waitcnt vmcnt(" #N ")" ::: "memory");        \
                 __builtin_amdgcn_sched_barrier(0)
      ISSUE8(R0, 0);
      ISSUE8(R1, 4);
      WAITV(8);  MFMA8(R0, 0);
      ISSUE8(R0, 8);
      WAITV(8);  MFMA8(R1, 4);
      ISSUE8(R1, 12);
      WAITV(8);  MFMA8(R0, 8);
      WAITV(0);  MFMA8(R1, 12);
#undef ISSUE8
#undef MFMA8
#undef WAITV
    }

    // K-half partials -> LDS (stride 132: lk-pairs 2-way alias = free)
    {
      float (*Cb)[CPAD] = kh ? C1 : C0;
#pragma unroll
      for (int mf = 0; mf < 2; mf++)
#pragma unroll
        for (int nf = 0; nf < 2; nf++)
#pragma unroll
          for (int r = 0; r < 4; r++)
            Cb[mf * 16 + lk * 4 + r][wc * 32 + nf * 16 + l15] = acc[mf][nf][r];
    }
    __syncthreads();

    // fused cell update: thread -> (row rloc, h pair 2hp,2hp+1)
    {
      const float* p0 = &C0[rloc][hp * 8];
      const float* p1 = &C1[rloc][hp * 8];
      f32x4 u0 = *(const f32x4*)p0;
      f32x4 u1 = *(const f32x4*)(p0 + 4);
      f32x4 v0 = *(const f32x4*)p1;
      f32x4 v1 = *(const f32x4*)(p1 + 4);
      float gi0 = u0[0] + v0[0] + bv[0];
      float gf0 = u0[1] + v0[1] + bv[1];
      float gg0 = u0[2] + v0[2] + bv[2];
      float go0 = u0[3] + v0[3] + bv[3];
      float gi1 = u1[0] + v1[0] + bv[4];
      float gf1 = u1[1] + v1[1] + bv[5];
      float gg1 = u1[2] + v1[2] + bv[6];
      float go1 = u1[3] + v1[3] + bv[7];

      float i0 = 1.f / (1.f + __expf(-gi0));
      float f0 = 1.f / (1.f + __expf(-gf0));
      float e0 = __expf(-2.f * fabsf(gg0));
      float tg0 = copysignf((1.f - e0) / (1.f + e0), gg0);
      float o0 = 1.f / (1.f + __expf(-go0));
      c0 = f0 * c0 + i0 * tg0;
      float ec0 = __expf(-2.f * fabsf(c0));
      float th0 = copysignf((1.f - ec0) / (1.f + ec0), c0);
      float h0 = o0 * th0;

      float i1 = 1.f / (1.f + __expf(-gi1));
      float f1 = 1.f / (1.f + __expf(-gf1));
      float e1 = __expf(-2.f * fabsf(gg1));
      float tg1 = copysignf((1.f - e1) / (1.f + e1), gg1);
      float o1 = 1.f / (1.f + __expf(-go1));
      c1 = f1 * c1 + i1 * tg1;
      float ec1 = __expf(-2.f * fabsf(c1));
      float th1 = copysignf((1.f - ec1) / (1.f + ec1), c1);
      float h1 = o1 * th1;

      union { f16 h[2]; unsigned int u; } pk;
      pk.h[0] = (f16)h0; pk.h[1] = (f16)h1;
      __hip_atomic_store(hdst_base + (size_t)(t + 1) * (BH / 2), pk.u,
                         __ATOMIC_RELAXED, __HIP_MEMORY_SCOPE_AGENT);
    }
    // __syncthreads drains vmcnt(0): all waves' sc0sc1 h-stores ACKed at LLC
    // before any thread proceeds -> RELAXED flag add is ordered-enough.
    __syncthreads();
    if (tid == 0)
      __hip_atomic_fetch_add(done + t * 16 + mb, 1, __ATOMIC_RELAXED,
                             __HIP_MEMORY_SCOPE_AGENT);
  }
}

// ---------------------------------------------------------------------------
// Tail: cosine-similarity attention (h_all is f16, layout-agnostic reductions)
// ---------------------------------------------------------------------------
__global__ void k_dots(const f16* __restrict__ h_all, float* __restrict__ part) {
  int t = blockIdx.x, s = blockIdx.y;
  const f16x8* ht = (const f16x8*)(h_all + (size_t)t * BH) + (size_t)s * 8192;
  const f16x8* hf = (const f16x8*)(h_all + (size_t)127 * BH) + (size_t)s * 8192;
  float sn = 0.f, sq = 0.f;
  for (int i = threadIdx.x; i < 8192; i += 256) {
    f16x8 a = ht[i], b = hf[i];
#pragma unroll
    for (int e = 0; e < 8; e++) {
      float fa = (float)a[e], fb = (float)b[e];
      sn += fa * fb; sq += fa * fa;
    }
  }
  for (int off = 32; off; off >>= 1) {
    sn += __shfl_down(sn, off);
    sq += __shfl_down(sq, off);
  }
  __shared__ float red[8];
  int wid = threadIdx.x >> 6;
  if ((threadIdx.x & 63) == 0) { red[wid] = sn; red[4 + wid] = sq; }
  __syncthreads();
  if (threadIdx.x == 0) {
    part[t * 8 + s]     = red[0] + red[1] + red[2] + red[3];
    part[t * 8 + 4 + s] = red[4] + red[5] + red[6] + red[7];
  }
}

__global__ void k_softmax(float* __restrict__ part) {
  __shared__ float sn_s[128], sq_s[128];
  int t = threadIdx.x;
  if (t < 128) {
    float sn = part[t * 8 + 0] + part[t * 8 + 1] + part[t * 8 + 2] + part[t * 8 + 3];
    float sq = part[t * 8 + 4] + part[t * 8 + 5] + part[t * 8 + 6] + part[t * 8 + 7];
    sn_s[t] = sn; sq_s[t] = sq;
  }
  __syncthreads();
  if (t == 0) {
    float nf = fmaxf(sqrtf(sq_s[127]), 1e-8f);
    float m = -1e30f;
    for (int i = 0; i < TSTEPS; i++) {
      float np = fmaxf(sqrtf(sq_s[i]), 1e-8f);
      sn_s[i] = sn_s[i] / (np * nf);
      m = fmaxf(m, sn_s[i]);
    }
    float ssum = 0.f;
    for (int i = 0; i < TSTEPS; i++) { float e = __expf(sn_s[i] - m); sn_s[i] = e; ssum += e; }
    float inv = 1.f / ssum;
    for (int i = 0; i < TSTEPS; i++) part[1024 + i] = sn_s[i] * inv;
  }
}

__global__ void k_out(const f16* __restrict__ h_all, const float* __restrict__ part,
                      float* __restrict__ out) {
  __shared__ float al[TSTEPS];
  if (threadIdx.x < TSTEPS) al[threadIdx.x] = part[1024 + threadIdx.x];
  __syncthreads();
  int g = blockIdx.x * blockDim.x + threadIdx.x;   // 0..32767
  int kc = g >> 9, row = g & 511;
  float s[8] = {0.f, 0.f, 0.f, 0.f, 0.f, 0.f, 0.f, 0.f};
  for (int t = 1; t < TSTEPS; t++) {               // t=0 is all-zero h0
    f16x8 v = *(const f16x8*)(h_all + (size_t)t * BH + (size_t)kc * 4096 + row * 8);
    float a = al[t];
#pragma unroll
    for (int e = 0; e < 8; e++) s[e] += a * (float)v[e];
  }
  float* o = out + (size_t)row * 512 + kc * 8;
  f32x4 lo = {s[0], s[1], s[2], s[3]}, hi = {s[4], s[5], s[6], s[7]};
  *(f32x4*)o = lo;
  *(f32x4*)(o + 4) = hi;
}

// ---------------------------------------------------------------------------
extern "C" void kernel_launch(void* const* d_in, const int* in_sizes, int n_in,
                              void* d_out, int out_size, void* d_ws, size_t ws_size,
                              hipStream_t stream) {
  const float* X    = (const float*)d_in[0];
  const float* W_ih = (const float*)d_in[1];
  const float* W_hh = (const float*)d_in[2];
  const float* b_ih = (const float*)d_in[3];
  const float* b_hh = (const float*)d_in[4];

  char* ws = (char*)d_ws;
  size_t off = 0;
  auto alloc = [&](size_t bytes) -> void* {
    void* p = ws + off;
    off = (off + bytes + 255) & ~(size_t)255;
    return p;
  };
  f16*   W16B  = (f16*)  alloc((size_t)2048 * 1024 * 2);    // 4 MB
  float* biasR = (float*)alloc(2048 * 4);                   // 8 KB
  f16*   XT    = (f16*)  alloc((size_t)TSTEPS * BH * 2);    // 66 MB
  f16*   h_all = (f16*)  alloc((size_t)T_DIM * BH * 2);     // 64 MB
  int*   done  = (int*)  alloc(TSTEPS * 16 * 4);            // 8 KB
  float* part  = (float*)alloc(2048 * 4);                   // 8 KB

  hipMemsetAsync(h_all, 0, (size_t)BH * 2, stream);   // h_all[0] = h0 = 0
  hipMemsetAsync(done,  0, TSTEPS * 16 * 4, stream);

  k_prep_w<<<1024, 256, 0, stream>>>(W_ih, W_hh, W16B);
  k_prep_b<<<8, 256, 0, stream>>>(b_ih, b_hh, biasR);
  k_prep_x<<<(TSTEPS * 512 * 64) / 256, 256, 0, stream>>>(X, XT);

  k_lstm<<<256, 512, 0, stream>>>(XT, h_all, W16B, biasR, done);

  k_dots<<<dim3(128, 4), 256, 0, stream>>>(h_all, part);
  k_softmax<<<1, 128, 0, stream>>>(part);
  k_out<<<128, 256, 0, stream>>>(h_all, part, (float*)d_out);
}